// Round 8
// baseline (2561.825 us; speedup 1.0000x reference)
//
#include <hip/hip_runtime.h>
#include <hip/hip_bf16.h>

#define NFEAT 256
#define NHID  128
#define NCLS  10
#define CONV_TIME 30
#define NSLICE 8          // feature slices == XCD count
#define SFEAT  16         // NHID / NSLICE; 64B rows
#define NBUCK  32         // degree buckets (plen/8, clamped)

// ---------------------------------------------------------------- degree histogram, dst-range partitioned
// block (b&7) owns dst range [part*n/8, (part+1)*n/8): every cnt line is
// written by ONE XCD only (blockIdx%8 -> XCD round-robin), so dirty lines
// don't ping-pong between non-coherent per-XCD L2s.
__global__ void deg_kernel(const int* __restrict__ ei, int* __restrict__ cnt, int E, int n) {
    int part = blockIdx.x & 7;
    int e = (blockIdx.x >> 3) * blockDim.x + threadIdx.x;
    int lo = (int)(((long long)part * n) >> 3);
    int hi = (int)(((long long)(part + 1) * n) >> 3);
    if (e < E) {
        int d = ei[(size_t)E + e];
        if (d >= lo && d < hi) atomicAdd(&cnt[d], 1);
    }
}

// ---------------------------------------------------------------- dinv = 1/sqrt(deg+1)
__global__ void dinv_kernel(const int* __restrict__ cnt, float* __restrict__ dinv, int n) {
    int i = blockIdx.x * blockDim.x + threadIdx.x;
    if (i < n) {
        float deg = (float)(cnt[i] + 1);
        dinv[i] = 1.0f / sqrtf(deg);
    }
}

// ---------------------------------------------------------------- padded segment allocation (wave-aggregated atomic)
__global__ void alloc_kernel(const int* __restrict__ cnt, int* __restrict__ alloc,
                             int* __restrict__ pbeg, int* __restrict__ plen,
                             int* __restrict__ pos, int n) {
    int i    = blockIdx.x * blockDim.x + threadIdx.x;
    int lane = threadIdx.x & 63;
    int pl   = 0;
    if (i < n) pl = (cnt[i] + 7) & ~7;
    int v = pl;
#pragma unroll
    for (int d = 1; d < 64; d <<= 1) {
        int t = __shfl_up(v, d, 64);
        if (lane >= d) v += t;
    }
    int total = __shfl(v, 63, 64);
    int excl  = v - pl;
    int base  = 0;
    if (lane == 63) base = atomicAdd(alloc, total);
    base = __shfl(base, 63, 64);
    if (i < n) {
        int seg = base + excl;
        pbeg[i] = seg;
        plen[i] = pl;
        pos[i]  = seg;
    }
}

// ---------------------------------------------------------------- degree-bucket histogram (LDS + merge)
__global__ void hist_kernel(const int* __restrict__ plen, int* __restrict__ bcnt, int n) {
    __shared__ int lh[NBUCK];
    int tid = threadIdx.x;
    if (tid < NBUCK) lh[tid] = 0;
    __syncthreads();
    int i = blockIdx.x * blockDim.x + tid;
    if (i < n) {
        int b = min(plen[i] >> 3, NBUCK - 1);
        atomicAdd(&lh[b], 1);
    }
    __syncthreads();
    if (tid < NBUCK && lh[tid]) atomicAdd(&bcnt[tid], lh[tid]);
}

// ---------------------------------------------------------------- 32-bucket exclusive scan
__global__ void scan32_kernel(const int* __restrict__ bcnt, int* __restrict__ bpos) {
    if (threadIdx.x == 0) {
        int a = 0;
        for (int b = 0; b < NBUCK; ++b) { bpos[b] = a; a += bcnt[b]; }
    }
}

// ---------------------------------------------------------------- place nodes into degree-sorted order
// wave-aggregated per-bucket atomics (<=32 atomics/wave). nperm[p]=node, rank[node]=p.
__global__ void place_kernel(const int* __restrict__ plen, int* __restrict__ bpos,
                             int* __restrict__ nperm, int* __restrict__ rank, int n) {
    int i    = blockIdx.x * blockDim.x + threadIdx.x;
    int lane = threadIdx.x & 63;
    int b    = -1;
    if (i < n) b = min(plen[i] >> 3, NBUCK - 1);
#pragma unroll 1
    for (int bb = 0; bb < NBUCK; ++bb) {
        unsigned long long mask = __ballot(b == bb);
        if (mask == 0ULL) continue;
        int leader = __ffsll((unsigned long long)mask) - 1;
        int cnt    = __popcll(mask);
        int base   = 0;
        if (lane == leader) base = atomicAdd(&bpos[bb], cnt);
        base = __shfl(base, leader, 64);
        int r = __popcll(mask & ((1ULL << lane) - 1ULL));
        if (b == bb) {
            int p = base + r;
            nperm[p] = i;
            rank[i]  = p;
        }
    }
}

// ---------------------------------------------------------------- gather per-node metadata into sorted order
__global__ void gather_sorted_kernel(const int* __restrict__ nperm,
                                     const int* __restrict__ pbeg, const int* __restrict__ plen,
                                     const float* __restrict__ dinv,
                                     int* __restrict__ pbeg_s, int* __restrict__ plen_s,
                                     float* __restrict__ dinv_s, int n) {
    int i = blockIdx.x * blockDim.x + threadIdx.x;
    if (i < n) {
        int nd = nperm[i];
        pbeg_s[i] = pbeg[nd];
        plen_s[i] = plen[nd];
        dinv_s[i] = dinv[nd];
    }
}

// ---------------------------------------------------------------- pre-fill esrc with dummy id n
__global__ void fill_esrc_kernel(unsigned int* __restrict__ esrc32, unsigned int val, int nwords) {
    int i = blockIdx.x * blockDim.x + threadIdx.x;
    if (i < nwords) esrc32[i] = val;
}

// ---------------------------------------------------------------- scatter edges into CSR, dst-range partitioned
// esrc payload = rank[src] (sorted row id, ushort). Each esrc/pos line is
// written by exactly one XCD -> single writeback (R7: 111MB -> ~4MB).
__global__ void scatter_kernel(const int* __restrict__ ei, const int* __restrict__ rank,
                               int* __restrict__ pos, unsigned short* __restrict__ esrc,
                               int E, int n) {
    int part = blockIdx.x & 7;
    int e = (blockIdx.x >> 3) * blockDim.x + threadIdx.x;
    int lo = (int)(((long long)part * n) >> 3);
    int hi = (int)(((long long)(part + 1) * n) >> 3);
    if (e < E) {
        int d = ei[(size_t)E + e];
        if (d >= lo && d < hi) {
            int s = ei[e];
            int p = atomicAdd(&pos[d], 1);
            esrc[p] = (unsigned short)rank[s];
        }
    }
}

// ---------------------------------------------------------------- zero the dummy row (row n) in both g buffers
__global__ void init_dummy_kernel(float* __restrict__ hA, float* __restrict__ hB,
                                  int n, int np1) {
    int t = threadIdx.x;
    if (t < NSLICE * SFEAT) {
        int sl = t >> 4, f = t & 15;
        size_t idx = (size_t)sl * np1 * SFEAT + (size_t)n * SFEAT + f;
        hA[idx] = 0.0f;
        hB[idx] = 0.0f;
    }
}

// ---------------------------------------------------------------- g0 = dinv * (x @ W1 + b1), sliced + SORTED row layout
__global__ __launch_bounds__(256) void gemm1_kernel(const float* __restrict__ x,
                                                    const float* __restrict__ W1,
                                                    const float* __restrict__ b1,
                                                    const float* __restrict__ dinv,
                                                    const int* __restrict__ rank,
                                                    float* __restrict__ g, int M, int np1) {
    __shared__ float As[64][20];
    __shared__ float Bs[16][128];
    int tid = threadIdx.x;
    int m0  = blockIdx.x * 64;
    int tx  = tid & 15;
    int ty  = tid >> 4;
    int ar  = tid >> 2, aq = tid & 3;
    int br  = tid >> 4, bc = tid & 15;

    float acc[4][8];
#pragma unroll
    for (int i = 0; i < 4; ++i)
#pragma unroll
        for (int j = 0; j < 8; ++j) acc[i][j] = 0.0f;

    for (int kb = 0; kb < NFEAT; kb += 16) {
        float4 av = make_float4(0.f, 0.f, 0.f, 0.f);
        int arow = m0 + ar;
        if (arow < M) av = *(const float4*)(x + (size_t)arow * NFEAT + kb + aq * 4);
        *(float4*)&As[ar][aq * 4] = av;
        *(float4*)&Bs[br][bc * 8]     = *(const float4*)(W1 + (size_t)(kb + br) * NHID + bc * 8);
        *(float4*)&Bs[br][bc * 8 + 4] = *(const float4*)(W1 + (size_t)(kb + br) * NHID + bc * 8 + 4);
        __syncthreads();
#pragma unroll
        for (int k = 0; k < 16; ++k) {
            float a0 = As[ty * 4 + 0][k];
            float a1 = As[ty * 4 + 1][k];
            float a2 = As[ty * 4 + 2][k];
            float a3 = As[ty * 4 + 3][k];
            float4 b0 = *(float4*)&Bs[k][tx * 8];
            float4 b1v = *(float4*)&Bs[k][tx * 8 + 4];
            float bv[8] = {b0.x, b0.y, b0.z, b0.w, b1v.x, b1v.y, b1v.z, b1v.w};
            float avv[4] = {a0, a1, a2, a3};
#pragma unroll
            for (int i = 0; i < 4; ++i)
#pragma unroll
                for (int j = 0; j < 8; ++j)
                    acc[i][j] = fmaf(avv[i], bv[j], acc[i][j]);
        }
        __syncthreads();
    }
    int col0 = tx * 8;
    int sl   = col0 >> 4;
    int c0   = col0 & 15;
#pragma unroll
    for (int i = 0; i < 4; ++i) {
        int row = m0 + ty * 4 + i;
        if (row < M) {
            float dv = dinv[row];
            int   rk = rank[row];
            float* dst = g + (size_t)sl * np1 * SFEAT + (size_t)rk * SFEAT + c0;
#pragma unroll
            for (int j = 0; j < 8; ++j)
                dst[j] = dv * (acc[i][j] + b1[col0 + j]);
        }
    }
}

// ---------------------------------------------------------------- one propagation hop (sliced, sorted, node-parallel slots)
// Identical structure to R7 but node indices are degree-sorted positions:
// a wave's 16 slots have near-equal padded degree -> no divergence waste.
// All metadata (pbeg_s/plen_s/dinv_s) and g rows are contiguous in sorted order.
__global__ __launch_bounds__(256) void hop_kernel(const float* __restrict__ gin,
                                                  float* __restrict__ gout,
                                                  const int* __restrict__ pbeg_s,
                                                  const int* __restrict__ plen_s,
                                                  const unsigned short* __restrict__ esrc,
                                                  const float* __restrict__ dinv_s,
                                                  int n, int np1, int last) {
    int bid  = blockIdx.x;
    int sl   = bid & (NSLICE - 1);
    int grp  = (bid >> 3) * 4 + (threadIdx.x >> 6);   // 16-node group
    if (grp * 16 >= n) return;
    int lane = threadIdx.x & 63;
    int slot = lane >> 2;
    int fl   = lane & 3;
    int idx  = grp * 16 + slot;          // sorted node position
    bool valid = idx < n;
    int idxC = valid ? idx : n;
    const float4* __restrict__ gs4 = (const float4*)(gin + (size_t)sl * np1 * SFEAT);
    float4*       __restrict__ go4 = (float4*)(gout + (size_t)sl * np1 * SFEAT);

    int beg = 0, L = 0;
    if (valid) { beg = pbeg_s[idx]; L = plen_s[idx]; }

    float4 acc = make_float4(0.f, 0.f, 0.f, 0.f);
    const uint4* __restrict__ e4 = (const uint4*)esrc;
    for (int i = 0; i < L; i += 8) {
        uint4 w = e4[(beg + i) >> 3];          // 8 edge ids (sorted row ids)
        int s0 = w.x & 0xFFFF, s1 = w.x >> 16;
        int s2 = w.y & 0xFFFF, s3 = w.y >> 16;
        int s4 = w.z & 0xFFFF, s5 = w.z >> 16;
        int s6 = w.w & 0xFFFF, s7 = w.w >> 16;
        float4 v0 = gs4[(size_t)s0 * 4 + fl];
        float4 v1 = gs4[(size_t)s1 * 4 + fl];
        float4 v2 = gs4[(size_t)s2 * 4 + fl];
        float4 v3 = gs4[(size_t)s3 * 4 + fl];
        float4 v4 = gs4[(size_t)s4 * 4 + fl];
        float4 v5 = gs4[(size_t)s5 * 4 + fl];
        float4 v6 = gs4[(size_t)s6 * 4 + fl];
        float4 v7 = gs4[(size_t)s7 * 4 + fl];
        acc.x += v0.x + v1.x + v2.x + v3.x + v4.x + v5.x + v6.x + v7.x;
        acc.y += v0.y + v1.y + v2.y + v3.y + v4.y + v5.y + v6.y + v7.y;
        acc.z += v0.z + v1.z + v2.z + v3.z + v4.z + v5.z + v6.z + v7.z;
        acc.w += v0.w + v1.w + v2.w + v3.w + v4.w + v5.w + v6.w + v7.w;
    }
    float4 sf = gs4[(size_t)idxC * 4 + fl];
    acc.x += sf.x; acc.y += sf.y; acc.z += sf.z; acc.w += sf.w;
    float dv = valid ? dinv_s[idx] : 1.0f;
    float sc = last ? dv : dv * dv;
    acc.x *= sc; acc.y *= sc; acc.z *= sc; acc.w *= sc;
    if (valid) go4[(size_t)idx * 4 + fl] = acc;
}

// ---------------------------------------------------------------- out = relu(h) @ Wc + bc (sorted h -> scatter out)
__global__ __launch_bounds__(256) void cls_kernel(const float* __restrict__ h,
                                                  const float* __restrict__ Wc,
                                                  const float* __restrict__ bc,
                                                  const int* __restrict__ nperm,
                                                  float* __restrict__ out, int n, int np1) {
    __shared__ float wc[NHID * NCLS];
    __shared__ float bcs[NCLS];
    int tid = threadIdx.x;
    for (int i = tid; i < NHID * NCLS; i += 256) wc[i] = Wc[i];
    if (tid < NCLS) bcs[tid] = bc[tid];
    __syncthreads();
    int i = blockIdx.x * 256 + tid;
    if (i >= n) return;
    float acc[NCLS];
#pragma unroll
    for (int c = 0; c < NCLS; ++c) acc[c] = bcs[c];
#pragma unroll
    for (int s = 0; s < NSLICE; ++s) {
        const float4* hr = (const float4*)(h + ((size_t)s * np1 + i) * SFEAT);
#pragma unroll
        for (int q = 0; q < 4; ++q) {
            float4 v = hr[q];
            float vs[4] = {fmaxf(v.x, 0.f), fmaxf(v.y, 0.f), fmaxf(v.z, 0.f), fmaxf(v.w, 0.f)};
#pragma unroll
            for (int j = 0; j < 4; ++j)
#pragma unroll
                for (int c = 0; c < NCLS; ++c)
                    acc[c] = fmaf(vs[j], wc[(s * SFEAT + q * 4 + j) * NCLS + c], acc[c]);
        }
    }
    int nd = nperm[i];
#pragma unroll
    for (int c = 0; c < NCLS; ++c) out[(size_t)nd * NCLS + c] = acc[c];
}

// ----------------------------------------------------------------
static inline size_t align256(size_t x) { return (x + 255) & ~(size_t)255; }

extern "C" void kernel_launch(void* const* d_in, const int* in_sizes, int n_in,
                              void* d_out, int out_size, void* d_ws, size_t ws_size,
                              hipStream_t stream) {
    const float* x   = (const float*)d_in[0];
    const int*   ei  = (const int*)d_in[1];     // int64 in reference -> staged as int32
    const float* W1  = (const float*)d_in[2];
    const float* b1  = (const float*)d_in[3];
    const float* Wc  = (const float*)d_in[4];
    const float* bc  = (const float*)d_in[5];
    float*       out = (float*)d_out;

    const int N    = in_sizes[0] / NFEAT;   // 50000
    const int E    = in_sizes[1] / 2;       // 1600000
    const int NP1  = N + 1;                 // +1 dummy row per slice
    const int EPAD = E + 8 * N + 64;        // worst-case padded CSR size

    char* ws = (char*)d_ws;
    size_t off = 0;
    float*          hA     = (float*)(ws + off); off = align256(off + (size_t)NSLICE * NP1 * SFEAT * 4);
    float*          hB     = (float*)(ws + off); off = align256(off + (size_t)NSLICE * NP1 * SFEAT * 4);
    int*            cnt    = (int*)  (ws + off); off = align256(off + (size_t)(N + 256) * 4);  // + counters
    float*          dinv   = (float*)(ws + off); off = align256(off + (size_t)N * 4);
    int*            pbeg   = (int*)  (ws + off); off = align256(off + (size_t)N * 4);
    int*            plen   = (int*)  (ws + off); off = align256(off + (size_t)N * 4);
    int*            pos    = (int*)  (ws + off); off = align256(off + (size_t)N * 4);
    int*            nperm  = (int*)  (ws + off); off = align256(off + (size_t)N * 4);
    int*            rank   = (int*)  (ws + off); off = align256(off + (size_t)N * 4);
    int*            pbeg_s = (int*)  (ws + off); off = align256(off + (size_t)N * 4);
    int*            plen_s = (int*)  (ws + off); off = align256(off + (size_t)N * 4);
    float*          dinv_s = (float*)(ws + off); off = align256(off + (size_t)N * 4);
    unsigned short* esrc   = (unsigned short*)(ws + off); off = align256(off + (size_t)EPAD * 2);

    int* alloc = cnt + N;        // counters region (memset with cnt)
    int* bcnt  = cnt + N + 64;
    int* bpos  = cnt + N + 128;

    hipMemsetAsync(cnt, 0, (size_t)(N + 256) * 4, stream);

    int nbE = (E + 255) / 256;
    deg_kernel<<<8 * nbE, 256, 0, stream>>>(ei, cnt, E, N);
    dinv_kernel<<<(N + 255) / 256, 256, 0, stream>>>(cnt, dinv, N);
    alloc_kernel<<<(N + 255) / 256, 256, 0, stream>>>(cnt, alloc, pbeg, plen, pos, N);
    hist_kernel<<<(N + 255) / 256, 256, 0, stream>>>(plen, bcnt, N);
    scan32_kernel<<<1, 64, 0, stream>>>(bcnt, bpos);
    place_kernel<<<(N + 255) / 256, 256, 0, stream>>>(plen, bpos, nperm, rank, N);
    gather_sorted_kernel<<<(N + 255) / 256, 256, 0, stream>>>(nperm, pbeg, plen, dinv,
                                                              pbeg_s, plen_s, dinv_s, N);
    {
        unsigned int v = ((unsigned)N << 16) | (unsigned)N;
        int nwords = EPAD / 2;
        fill_esrc_kernel<<<(nwords + 255) / 256, 256, 0, stream>>>((unsigned int*)esrc, v, nwords);
    }
    scatter_kernel<<<8 * nbE, 256, 0, stream>>>(ei, rank, pos, esrc, E, N);
    init_dummy_kernel<<<1, 256, 0, stream>>>(hA, hB, N, NP1);

    gemm1_kernel<<<(N + 63) / 64, 256, 0, stream>>>(x, W1, b1, dinv, rank, hA, N, NP1);

    int ngrp = (N + 15) / 16;                     // 16 nodes per wave
    int hop_blocks = NSLICE * ((ngrp + 3) / 4);   // 4 waves per block
    for (int i = 0; i < CONV_TIME; ++i) {
        const float* gi = (i & 1) ? hB : hA;
        float*       go = (i & 1) ? hA : hB;
        hop_kernel<<<hop_blocks, 256, 0, stream>>>(gi, go, pbeg_s, plen_s, esrc, dinv_s, N, NP1,
                                                   (i == CONV_TIME - 1) ? 1 : 0);
    }

    cls_kernel<<<(N + 255) / 256, 256, 0, stream>>>(hA, Wc, bc, nperm, out, N, NP1);
}

// Round 10
// 2358.669 us; speedup vs baseline: 1.0861x; 1.0861x over previous
//
#include <hip/hip_runtime.h>
#include <hip/hip_bf16.h>

#define NFEAT 256
#define NHID  128
#define NCLS  10
#define CONV_TIME 30
#define NSLICE 8          // feature slices == XCD count
#define SFEAT  16         // NHID / NSLICE; 64B rows
#define NBUCK  32         // degree buckets (plen/8, clamped)

// ---------------------------------------------------------------- degree histogram, dst-range partitioned
// block (b&7) owns dst range [part*n/8,(part+1)*n/8): each cnt line is written
// by ONE XCD only -> no dirty-line ping-pong between non-coherent L2s (R7 fix).
__global__ void deg_kernel(const int* __restrict__ ei, int* __restrict__ cnt, int E, int n) {
    int part = blockIdx.x & 7;
    int e = (blockIdx.x >> 3) * blockDim.x + threadIdx.x;
    int lo = (int)(((long long)part * n) >> 3);
    int hi = (int)(((long long)(part + 1) * n) >> 3);
    if (e < E) {
        int d = ei[(size_t)E + e];
        if (d >= lo && d < hi) atomicAdd(&cnt[d], 1);
    }
}

// ---------------------------------------------------------------- dinv = 1/sqrt(deg+1)
__global__ void dinv_kernel(const int* __restrict__ cnt, float* __restrict__ dinv, int n) {
    int i = blockIdx.x * blockDim.x + threadIdx.x;
    if (i < n) {
        float deg = (float)(cnt[i] + 1);
        dinv[i] = 1.0f / sqrtf(deg);
    }
}

// ---------------------------------------------------------------- degree-bucket histogram (LDS + merge)
__global__ void hist_kernel(const int* __restrict__ cnt, int* __restrict__ bcnt, int n) {
    __shared__ int lh[NBUCK];
    int tid = threadIdx.x;
    if (tid < NBUCK) lh[tid] = 0;
    __syncthreads();
    int i = blockIdx.x * blockDim.x + tid;
    if (i < n) {
        int b = min((cnt[i] + 7) >> 3, NBUCK - 1);
        atomicAdd(&lh[b], 1);
    }
    __syncthreads();
    if (tid < NBUCK && lh[tid]) atomicAdd(&bcnt[tid], lh[tid]);
}

// ---------------------------------------------------------------- 32-bucket exclusive scan
__global__ void scan32_kernel(const int* __restrict__ bcnt, int* __restrict__ bpos) {
    if (threadIdx.x == 0) {
        int a = 0;
        for (int b = 0; b < NBUCK; ++b) { bpos[b] = a; a += bcnt[b]; }
    }
}

// ---------------------------------------------------------------- place nodes into degree-sorted order
// wave-aggregated per-bucket atomics. nperm[p]=node, rank[node]=p.
__global__ void place_kernel(const int* __restrict__ cnt, int* __restrict__ bpos,
                             int* __restrict__ nperm, int* __restrict__ rank, int n) {
    int i    = blockIdx.x * blockDim.x + threadIdx.x;
    int lane = threadIdx.x & 63;
    int b    = -1;
    if (i < n) b = min((cnt[i] + 7) >> 3, NBUCK - 1);
#pragma unroll 1
    for (int bb = 0; bb < NBUCK; ++bb) {
        unsigned long long mask = __ballot(b == bb);
        if (mask == 0ULL) continue;
        int leader = __ffsll((unsigned long long)mask) - 1;
        int c      = __popcll(mask);
        int base   = 0;
        if (lane == leader) base = atomicAdd(&bpos[bb], c);
        base = __shfl(base, leader, 64);
        int r = __popcll(mask & ((1ULL << lane) - 1ULL));
        if (b == bb) {
            int p = base + r;
            nperm[p] = i;
            rank[i]  = p;
        }
    }
}

// ---------------------------------------------------------------- allocate esrc segments in SORTED order
// i = sorted position. Contiguous segments for consecutive sorted positions
// (within each 64-wide wave; waves placed by one atomic each) -> a hop wave's
// 16 slots read ADJACENT esrc segments (R8's regression was losing this).
// Also emits pos[orig]=segment start for the scatter, seg_s=(beg,len), dinv_s.
__global__ void alloc_sorted_kernel(const int* __restrict__ nperm, const int* __restrict__ cnt,
                                    const float* __restrict__ dinv, int* __restrict__ alloc,
                                    int2* __restrict__ seg_s, float* __restrict__ dinv_s,
                                    int* __restrict__ pos, int n) {
    int i    = blockIdx.x * blockDim.x + threadIdx.x;
    int lane = threadIdx.x & 63;
    int node = 0, pl = 0;
    if (i < n) {
        node = nperm[i];
        pl   = (cnt[node] + 7) & ~7;
    }
    int v = pl;
#pragma unroll
    for (int d = 1; d < 64; d <<= 1) {
        int t = __shfl_up(v, d, 64);
        if (lane >= d) v += t;
    }
    int total = __shfl(v, 63, 64);
    int excl  = v - pl;
    int base  = 0;
    if (lane == 63) base = atomicAdd(alloc, total);
    base = __shfl(base, 63, 64);
    if (i < n) {
        int beg = base + excl;
        seg_s[i]  = make_int2(beg, pl);
        dinv_s[i] = dinv[node];
        pos[node] = beg;
    }
}

// ---------------------------------------------------------------- pre-fill esrc with dummy id n
__global__ void fill_esrc_kernel(unsigned int* __restrict__ esrc32, unsigned int val, int nwords) {
    int i = blockIdx.x * blockDim.x + threadIdx.x;
    if (i < nwords) esrc32[i] = val;
}

// ---------------------------------------------------------------- scatter edges into CSR, dst-range partitioned
// esrc payload = rank[src] (sorted row id, ushort).
__global__ void scatter_kernel(const int* __restrict__ ei, const int* __restrict__ rank,
                               int* __restrict__ pos, unsigned short* __restrict__ esrc,
                               int E, int n) {
    int part = blockIdx.x & 7;
    int e = (blockIdx.x >> 3) * blockDim.x + threadIdx.x;
    int lo = (int)(((long long)part * n) >> 3);
    int hi = (int)(((long long)(part + 1) * n) >> 3);
    if (e < E) {
        int d = ei[(size_t)E + e];
        if (d >= lo && d < hi) {
            int s = ei[e];
            int p = atomicAdd(&pos[d], 1);
            esrc[p] = (unsigned short)rank[s];
        }
    }
}

// ---------------------------------------------------------------- zero the dummy row (row n) in both g buffers
__global__ void init_dummy_kernel(float* __restrict__ hA, float* __restrict__ hB,
                                  int n, int np1) {
    int t = threadIdx.x;
    if (t < NSLICE * SFEAT) {
        int sl = t >> 4, f = t & 15;
        size_t idx = (size_t)sl * np1 * SFEAT + (size_t)n * SFEAT + f;
        hA[idx] = 0.0f;
        hB[idx] = 0.0f;
    }
}

// ---------------------------------------------------------------- g0 = dinv * (x @ W1 + b1), sliced + SORTED row layout
__global__ __launch_bounds__(256) void gemm1_kernel(const float* __restrict__ x,
                                                    const float* __restrict__ W1,
                                                    const float* __restrict__ b1,
                                                    const float* __restrict__ dinv,
                                                    const int* __restrict__ rank,
                                                    float* __restrict__ g, int M, int np1) {
    __shared__ float As[64][20];
    __shared__ float Bs[16][128];
    int tid = threadIdx.x;
    int m0  = blockIdx.x * 64;
    int tx  = tid & 15;
    int ty  = tid >> 4;
    int ar  = tid >> 2, aq = tid & 3;
    int br  = tid >> 4, bc = tid & 15;

    float acc[4][8];
#pragma unroll
    for (int i = 0; i < 4; ++i)
#pragma unroll
        for (int j = 0; j < 8; ++j) acc[i][j] = 0.0f;

    for (int kb = 0; kb < NFEAT; kb += 16) {
        float4 av = make_float4(0.f, 0.f, 0.f, 0.f);
        int arow = m0 + ar;
        if (arow < M) av = *(const float4*)(x + (size_t)arow * NFEAT + kb + aq * 4);
        *(float4*)&As[ar][aq * 4] = av;
        *(float4*)&Bs[br][bc * 8]     = *(const float4*)(W1 + (size_t)(kb + br) * NHID + bc * 8);
        *(float4*)&Bs[br][bc * 8 + 4] = *(const float4*)(W1 + (size_t)(kb + br) * NHID + bc * 8 + 4);
        __syncthreads();
#pragma unroll
        for (int k = 0; k < 16; ++k) {
            float a0 = As[ty * 4 + 0][k];
            float a1 = As[ty * 4 + 1][k];
            float a2 = As[ty * 4 + 2][k];
            float a3 = As[ty * 4 + 3][k];
            float4 b0 = *(float4*)&Bs[k][tx * 8];
            float4 b1v = *(float4*)&Bs[k][tx * 8 + 4];
            float bv[8] = {b0.x, b0.y, b0.z, b0.w, b1v.x, b1v.y, b1v.z, b1v.w};
            float avv[4] = {a0, a1, a2, a3};
#pragma unroll
            for (int i = 0; i < 4; ++i)
#pragma unroll
                for (int j = 0; j < 8; ++j)
                    acc[i][j] = fmaf(avv[i], bv[j], acc[i][j]);
        }
        __syncthreads();
    }
    int col0 = tx * 8;
    int sl   = col0 >> 4;
    int c0   = col0 & 15;
#pragma unroll
    for (int i = 0; i < 4; ++i) {
        int row = m0 + ty * 4 + i;
        if (row < M) {
            float dv = dinv[row];
            int   rk = rank[row];
            float* dst = g + (size_t)sl * np1 * SFEAT + (size_t)rk * SFEAT + c0;
#pragma unroll
            for (int j = 0; j < 8; ++j)
                dst[j] = dv * (acc[i][j] + b1[col0 + j]);
        }
    }
}

// ---------------------------------------------------------------- one propagation hop (sliced, sorted, node-parallel slots)
// blockIdx&7 = feature slice -> XCD-local 3.2MB working set (R4 proof).
// Wave = 16 node-slots x 4 lanes (float4 of the slot's 16-feat row). Sorted
// positions give equal slot degrees AND (with sorted alloc) adjacent esrc
// segments per wave. 8 independent gathers in flight per slot iteration.
__global__ __launch_bounds__(256) void hop_kernel(const float* __restrict__ gin,
                                                  float* __restrict__ gout,
                                                  const int2* __restrict__ seg_s,
                                                  const unsigned short* __restrict__ esrc,
                                                  const float* __restrict__ dinv_s,
                                                  int n, int np1, int last) {
    int bid  = blockIdx.x;
    int sl   = bid & (NSLICE - 1);
    int grp  = (bid >> 3) * 4 + (threadIdx.x >> 6);   // 16-node group
    if (grp * 16 >= n) return;
    int lane = threadIdx.x & 63;
    int slot = lane >> 2;
    int fl   = lane & 3;
    int idx  = grp * 16 + slot;          // sorted node position
    bool valid = idx < n;
    int idxC = valid ? idx : n;
    const float4* __restrict__ gs4 = (const float4*)(gin + (size_t)sl * np1 * SFEAT);
    float4*       __restrict__ go4 = (float4*)(gout + (size_t)sl * np1 * SFEAT);

    int2 seg = valid ? seg_s[idx] : make_int2(0, 0);
    int beg = seg.x, L = seg.y;

    float4 acc = make_float4(0.f, 0.f, 0.f, 0.f);
    const uint4* __restrict__ e4 = (const uint4*)esrc;
    for (int i = 0; i < L; i += 8) {
        uint4 w = e4[(beg + i) >> 3];          // 8 edge ids (sorted row ids)
        int s0 = w.x & 0xFFFF, s1 = w.x >> 16;
        int s2 = w.y & 0xFFFF, s3 = w.y >> 16;
        int s4 = w.z & 0xFFFF, s5 = w.z >> 16;
        int s6 = w.w & 0xFFFF, s7 = w.w >> 16;
        float4 v0 = gs4[(size_t)s0 * 4 + fl];
        float4 v1 = gs4[(size_t)s1 * 4 + fl];
        float4 v2 = gs4[(size_t)s2 * 4 + fl];
        float4 v3 = gs4[(size_t)s3 * 4 + fl];
        float4 v4 = gs4[(size_t)s4 * 4 + fl];
        float4 v5 = gs4[(size_t)s5 * 4 + fl];
        float4 v6 = gs4[(size_t)s6 * 4 + fl];
        float4 v7 = gs4[(size_t)s7 * 4 + fl];
        acc.x += v0.x + v1.x + v2.x + v3.x + v4.x + v5.x + v6.x + v7.x;
        acc.y += v0.y + v1.y + v2.y + v3.y + v4.y + v5.y + v6.y + v7.y;
        acc.z += v0.z + v1.z + v2.z + v3.z + v4.z + v5.z + v6.z + v7.z;
        acc.w += v0.w + v1.w + v2.w + v3.w + v4.w + v5.w + v6.w + v7.w;
    }
    float4 sf = gs4[(size_t)idxC * 4 + fl];
    acc.x += sf.x; acc.y += sf.y; acc.z += sf.z; acc.w += sf.w;
    float dv = valid ? dinv_s[idx] : 1.0f;
    float sc = last ? dv : dv * dv;
    acc.x *= sc; acc.y *= sc; acc.z *= sc; acc.w *= sc;
    if (valid) go4[(size_t)idx * 4 + fl] = acc;
}

// ---------------------------------------------------------------- out = relu(h) @ Wc + bc (sorted h -> scatter out)
__global__ __launch_bounds__(256) void cls_kernel(const float* __restrict__ h,
                                                  const float* __restrict__ Wc,
                                                  const float* __restrict__ bc,
                                                  const int* __restrict__ nperm,
                                                  float* __restrict__ out, int n, int np1) {
    __shared__ float wc[NHID * NCLS];
    __shared__ float bcs[NCLS];
    int tid = threadIdx.x;
    for (int i = tid; i < NHID * NCLS; i += 256) wc[i] = Wc[i];
    if (tid < NCLS) bcs[tid] = bc[tid];
    __syncthreads();
    int i = blockIdx.x * 256 + tid;
    if (i >= n) return;
    float acc[NCLS];
#pragma unroll
    for (int c = 0; c < NCLS; ++c) acc[c] = bcs[c];
#pragma unroll
    for (int s = 0; s < NSLICE; ++s) {
        const float4* hr = (const float4*)(h + ((size_t)s * np1 + i) * SFEAT);
#pragma unroll
        for (int q = 0; q < 4; ++q) {
            float4 v = hr[q];
            float vs[4] = {fmaxf(v.x, 0.f), fmaxf(v.y, 0.f), fmaxf(v.z, 0.f), fmaxf(v.w, 0.f)};
#pragma unroll
            for (int j = 0; j < 4; ++j)
#pragma unroll
                for (int c = 0; c < NCLS; ++c)
                    acc[c] = fmaf(vs[j], wc[(s * SFEAT + q * 4 + j) * NCLS + c], acc[c]);
        }
    }
    int nd = nperm[i];
#pragma unroll
    for (int c = 0; c < NCLS; ++c) out[(size_t)nd * NCLS + c] = acc[c];
}

// ----------------------------------------------------------------
static inline size_t align256(size_t x) { return (x + 255) & ~(size_t)255; }

extern "C" void kernel_launch(void* const* d_in, const int* in_sizes, int n_in,
                              void* d_out, int out_size, void* d_ws, size_t ws_size,
                              hipStream_t stream) {
    const float* x   = (const float*)d_in[0];
    const int*   ei  = (const int*)d_in[1];     // int64 in reference -> staged as int32
    const float* W1  = (const float*)d_in[2];
    const float* b1  = (const float*)d_in[3];
    const float* Wc  = (const float*)d_in[4];
    const float* bc  = (const float*)d_in[5];
    float*       out = (float*)d_out;

    const int N    = in_sizes[0] / NFEAT;   // 50000
    const int E    = in_sizes[1] / 2;       // 1600000
    const int NP1  = N + 1;                 // +1 dummy row per slice
    const int EPAD = E + 8 * N + 64;        // worst-case padded CSR size

    char* ws = (char*)d_ws;
    size_t off = 0;
    float*          hA     = (float*)(ws + off); off = align256(off + (size_t)NSLICE * NP1 * SFEAT * 4);
    float*          hB     = (float*)(ws + off); off = align256(off + (size_t)NSLICE * NP1 * SFEAT * 4);
    int*            cnt    = (int*)  (ws + off); off = align256(off + (size_t)(N + 256) * 4);  // + counters
    float*          dinv   = (float*)(ws + off); off = align256(off + (size_t)N * 4);
    int*            pos    = (int*)  (ws + off); off = align256(off + (size_t)N * 4);
    int*            nperm  = (int*)  (ws + off); off = align256(off + (size_t)N * 4);
    int*            rank   = (int*)  (ws + off); off = align256(off + (size_t)N * 4);
    int2*           seg_s  = (int2*) (ws + off); off = align256(off + (size_t)N * 8);
    float*          dinv_s = (float*)(ws + off); off = align256(off + (size_t)N * 4);
    unsigned short* esrc   = (unsigned short*)(ws + off); off = align256(off + (size_t)EPAD * 2);

    int* alloc = cnt + N;        // counters region (memset with cnt)
    int* bcnt  = cnt + N + 64;
    int* bpos  = cnt + N + 128;

    hipMemsetAsync(cnt, 0, (size_t)(N + 256) * 4, stream);

    int nbE = (E + 255) / 256;
    deg_kernel<<<8 * nbE, 256, 0, stream>>>(ei, cnt, E, N);
    dinv_kernel<<<(N + 255) / 256, 256, 0, stream>>>(cnt, dinv, N);
    hist_kernel<<<(N + 255) / 256, 256, 0, stream>>>(cnt, bcnt, N);
    scan32_kernel<<<1, 64, 0, stream>>>(bcnt, bpos);
    place_kernel<<<(N + 255) / 256, 256, 0, stream>>>(cnt, bpos, nperm, rank, N);
    alloc_sorted_kernel<<<(N + 255) / 256, 256, 0, stream>>>(nperm, cnt, dinv, alloc,
                                                             seg_s, dinv_s, pos, N);
    {
        unsigned int v = ((unsigned)N << 16) | (unsigned)N;
        int nwords = EPAD / 2;
        fill_esrc_kernel<<<(nwords + 255) / 256, 256, 0, stream>>>((unsigned int*)esrc, v, nwords);
    }
    scatter_kernel<<<8 * nbE, 256, 0, stream>>>(ei, rank, pos, esrc, E, N);
    init_dummy_kernel<<<1, 256, 0, stream>>>(hA, hB, N, NP1);

    gemm1_kernel<<<(N + 63) / 64, 256, 0, stream>>>(x, W1, b1, dinv, rank, hA, N, NP1);

    int ngrp = (N + 15) / 16;                     // 16 nodes per wave
    int hop_blocks = NSLICE * ((ngrp + 3) / 4);   // 4 waves per block
    for (int i = 0; i < CONV_TIME; ++i) {
        const float* gi = (i & 1) ? hB : hA;
        float*       go = (i & 1) ? hA : hB;
        hop_kernel<<<hop_blocks, 256, 0, stream>>>(gi, go, seg_s, esrc, dinv_s, N, NP1,
                                                   (i == CONV_TIME - 1) ? 1 : 0);
    }

    cls_kernel<<<(N + 255) / 256, 256, 0, stream>>>(hA, Wc, bc, nperm, out, N, NP1);
}

// Round 12
// 2329.232 us; speedup vs baseline: 1.0999x; 1.0126x over previous
//
#include <hip/hip_runtime.h>
#include <hip/hip_bf16.h>

#define NFEAT 256
#define NHID  128
#define NCLS  10
#define CONV_TIME 30
#define NSLICE 8          // feature slices == XCD count
#define SFEAT  16         // NHID / NSLICE; 64B rows
#define NBUCK  32         // degree buckets

// ---------------------------------------------------------------- degree histogram, dst-range partitioned
__global__ void deg_kernel(const int* __restrict__ ei, int* __restrict__ cnt, int E, int n) {
    int part = blockIdx.x & 7;
    int e = (blockIdx.x >> 3) * blockDim.x + threadIdx.x;
    int lo = (int)(((long long)part * n) >> 3);
    int hi = (int)(((long long)(part + 1) * n) >> 3);
    if (e < E) {
        int d = ei[(size_t)E + e];
        if (d >= lo && d < hi) atomicAdd(&cnt[d], 1);
    }
}

// ---------------------------------------------------------------- dinv = 1/sqrt(deg+1)
__global__ void dinv_kernel(const int* __restrict__ cnt, float* __restrict__ dinv, int n) {
    int i = blockIdx.x * blockDim.x + threadIdx.x;
    if (i < n) {
        float deg = (float)(cnt[i] + 1);
        dinv[i] = 1.0f / sqrtf(deg);
    }
}

// ---------------------------------------------------------------- degree-bucket histogram (LDS + merge)
__global__ void hist_kernel(const int* __restrict__ cnt, int* __restrict__ bcnt, int n) {
    __shared__ int lh[NBUCK];
    int tid = threadIdx.x;
    if (tid < NBUCK) lh[tid] = 0;
    __syncthreads();
    int i = blockIdx.x * blockDim.x + tid;
    if (i < n) {
        int b = min((cnt[i] + 7) >> 3, NBUCK - 1);
        atomicAdd(&lh[b], 1);
    }
    __syncthreads();
    if (tid < NBUCK && lh[tid]) atomicAdd(&bcnt[tid], lh[tid]);
}

// ---------------------------------------------------------------- 32-bucket exclusive scan
__global__ void scan32_kernel(const int* __restrict__ bcnt, int* __restrict__ bpos) {
    if (threadIdx.x == 0) {
        int a = 0;
        for (int b = 0; b < NBUCK; ++b) { bpos[b] = a; a += bcnt[b]; }
    }
}

// ---------------------------------------------------------------- place nodes into degree-sorted order
__global__ void place_kernel(const int* __restrict__ cnt, int* __restrict__ bpos,
                             int* __restrict__ nperm, int* __restrict__ rank, int n) {
    int i    = blockIdx.x * blockDim.x + threadIdx.x;
    int lane = threadIdx.x & 63;
    int b    = -1;
    if (i < n) b = min((cnt[i] + 7) >> 3, NBUCK - 1);
#pragma unroll 1
    for (int bb = 0; bb < NBUCK; ++bb) {
        unsigned long long mask = __ballot(b == bb);
        if (mask == 0ULL) continue;
        int leader = __ffsll((unsigned long long)mask) - 1;
        int c      = __popcll(mask);
        int base   = 0;
        if (lane == leader) base = atomicAdd(&bpos[bb], c);
        base = __shfl(base, leader, 64);
        int r = __popcll(mask & ((1ULL << lane) - 1ULL));
        if (b == bb) {
            int p = base + r;
            nperm[p] = i;
            rank[i]  = p;
        }
    }
}

// ---------------------------------------------------------------- allocate esrc segments in SORTED order
// pos_s indexed by SORTED position; scatter partitions by rank ranges, so both
// pos_s and esrc writes are contiguous per partition -> one XCD per line.
__global__ void alloc_sorted_kernel(const int* __restrict__ nperm, const int* __restrict__ cnt,
                                    const float* __restrict__ dinv, int* __restrict__ alloc,
                                    int2* __restrict__ seg_s, float* __restrict__ dinv_s,
                                    int* __restrict__ pos_s, int n) {
    int i    = blockIdx.x * blockDim.x + threadIdx.x;
    int lane = threadIdx.x & 63;
    int node = 0, pl = 0;
    if (i < n) {
        node = nperm[i];
        pl   = (cnt[node] + 7) & ~7;
    }
    int v = pl;
#pragma unroll
    for (int d = 1; d < 64; d <<= 1) {
        int t = __shfl_up(v, d, 64);
        if (lane >= d) v += t;
    }
    int total = __shfl(v, 63, 64);
    int excl  = v - pl;
    int base  = 0;
    if (lane == 63) base = atomicAdd(alloc, total);
    base = __shfl(base, 63, 64);
    if (i < n) {
        int beg = base + excl;
        seg_s[i]  = make_int2(beg, pl);
        dinv_s[i] = dinv[node];
        pos_s[i]  = beg;
    }
}

// ---------------------------------------------------------------- pre-fill esrc with dummy id n
__global__ void fill_esrc_kernel(unsigned int* __restrict__ esrc32, unsigned int val, int nwords) {
    int i = blockIdx.x * blockDim.x + threadIdx.x;
    if (i < nwords) esrc32[i] = val;
}

// ---------------------------------------------------------------- scatter edges into CSR, RANK-range partitioned
// Partition key = rank[d]; segments are allocated in sorted order, so each
// partition's esrc/pos_s writes form a contiguous region -> every 64B line is
// dirtied by exactly ONE XCD (fixes R10's 60MB writeback).
__global__ void scatter_kernel(const int* __restrict__ ei, const int* __restrict__ rank,
                               int* __restrict__ pos_s, unsigned short* __restrict__ esrc,
                               int E, int n) {
    int part = blockIdx.x & 7;
    int e = (blockIdx.x >> 3) * blockDim.x + threadIdx.x;
    int lo = (int)(((long long)part * n) >> 3);
    int hi = (int)(((long long)(part + 1) * n) >> 3);
    if (e < E) {
        int d = ei[(size_t)E + e];
        int r = rank[d];
        if (r >= lo && r < hi) {
            int s = ei[e];
            int p = atomicAdd(&pos_s[r], 1);
            esrc[p] = (unsigned short)rank[s];
        }
    }
}

// ---------------------------------------------------------------- zero the dummy row (row n) in both g buffers
__global__ void init_dummy_kernel(float* __restrict__ hA, float* __restrict__ hB,
                                  int n, int np1) {
    int t = threadIdx.x;
    if (t < NSLICE * SFEAT) {
        int sl = t >> 4, f = t & 15;
        size_t idx = (size_t)sl * np1 * SFEAT + (size_t)n * SFEAT + f;
        hA[idx] = 0.0f;
        hB[idx] = 0.0f;
    }
}

// ---------------------------------------------------------------- g0 = dinv * (x @ W1 + b1), sliced + SORTED row layout
__global__ __launch_bounds__(256) void gemm1_kernel(const float* __restrict__ x,
                                                    const float* __restrict__ W1,
                                                    const float* __restrict__ b1,
                                                    const float* __restrict__ dinv,
                                                    const int* __restrict__ rank,
                                                    float* __restrict__ g, int M, int np1) {
    __shared__ float As[64][20];
    __shared__ float Bs[16][128];
    int tid = threadIdx.x;
    int m0  = blockIdx.x * 64;
    int tx  = tid & 15;
    int ty  = tid >> 4;
    int ar  = tid >> 2, aq = tid & 3;
    int br  = tid >> 4, bc = tid & 15;

    float acc[4][8];
#pragma unroll
    for (int i = 0; i < 4; ++i)
#pragma unroll
        for (int j = 0; j < 8; ++j) acc[i][j] = 0.0f;

    for (int kb = 0; kb < NFEAT; kb += 16) {
        float4 av = make_float4(0.f, 0.f, 0.f, 0.f);
        int arow = m0 + ar;
        if (arow < M) av = *(const float4*)(x + (size_t)arow * NFEAT + kb + aq * 4);
        *(float4*)&As[ar][aq * 4] = av;
        *(float4*)&Bs[br][bc * 8]     = *(const float4*)(W1 + (size_t)(kb + br) * NHID + bc * 8);
        *(float4*)&Bs[br][bc * 8 + 4] = *(const float4*)(W1 + (size_t)(kb + br) * NHID + bc * 8 + 4);
        __syncthreads();
#pragma unroll
        for (int k = 0; k < 16; ++k) {
            float a0 = As[ty * 4 + 0][k];
            float a1 = As[ty * 4 + 1][k];
            float a2 = As[ty * 4 + 2][k];
            float a3 = As[ty * 4 + 3][k];
            float4 b0 = *(float4*)&Bs[k][tx * 8];
            float4 b1v = *(float4*)&Bs[k][tx * 8 + 4];
            float bv[8] = {b0.x, b0.y, b0.z, b0.w, b1v.x, b1v.y, b1v.z, b1v.w};
            float avv[4] = {a0, a1, a2, a3};
#pragma unroll
            for (int i = 0; i < 4; ++i)
#pragma unroll
                for (int j = 0; j < 8; ++j)
                    acc[i][j] = fmaf(avv[i], bv[j], acc[i][j]);
        }
        __syncthreads();
    }
    int col0 = tx * 8;
    int sl   = col0 >> 4;
    int c0   = col0 & 15;
#pragma unroll
    for (int i = 0; i < 4; ++i) {
        int row = m0 + ty * 4 + i;
        if (row < M) {
            float dv = dinv[row];
            int   rk = rank[row];
            float* dst = g + (size_t)sl * np1 * SFEAT + (size_t)rk * SFEAT + c0;
#pragma unroll
            for (int j = 0; j < 8; ++j)
                dst[j] = dv * (acc[i][j] + b1[col0 + j]);
        }
    }
}

// ---------------------------------------------------------------- one propagation hop (sliced, sorted, node-parallel slots)
// blockIdx&7 = feature slice -> XCD-local 3.2MB slice (R4 proof). Wave = 16
// node-slots x 4 lanes. Sorted positions: equal slot degrees + adjacent esrc
// segments per wave. GROUP ORDER REVERSED: high-degree (high sorted position)
// groups are dispatched first so the long-running waves start early and
// low-degree waves backfill -> shorter drain tail (degree sort had put all
// heavy nodes at the END of the dispatch).
__global__ __launch_bounds__(256) void hop_kernel(const float* __restrict__ gin,
                                                  float* __restrict__ gout,
                                                  const int2* __restrict__ seg_s,
                                                  const unsigned short* __restrict__ esrc,
                                                  const float* __restrict__ dinv_s,
                                                  int n, int np1, int last) {
    int bid  = blockIdx.x;
    int sl   = bid & (NSLICE - 1);
    int ngrp = (n + 15) >> 4;
    int grp  = (bid >> 3) * 4 + (threadIdx.x >> 6);
    if (grp >= ngrp) return;
    grp = ngrp - 1 - grp;                // high-degree groups first
    int lane = threadIdx.x & 63;
    int slot = lane >> 2;
    int fl   = lane & 3;
    int idx  = grp * 16 + slot;          // sorted node position
    bool valid = idx < n;
    int idxC = valid ? idx : n;
    const float4* __restrict__ gs4 = (const float4*)(gin + (size_t)sl * np1 * SFEAT);
    float4*       __restrict__ go4 = (float4*)(gout + (size_t)sl * np1 * SFEAT);

    int2 seg = valid ? seg_s[idx] : make_int2(0, 0);
    int beg = seg.x, L = seg.y;

    float4 acc = make_float4(0.f, 0.f, 0.f, 0.f);
    const uint4* __restrict__ e4 = (const uint4*)esrc;
    for (int i = 0; i < L; i += 8) {
        uint4 w = e4[(beg + i) >> 3];          // 8 edge ids (sorted row ids)
        int s0 = w.x & 0xFFFF, s1 = w.x >> 16;
        int s2 = w.y & 0xFFFF, s3 = w.y >> 16;
        int s4 = w.z & 0xFFFF, s5 = w.z >> 16;
        int s6 = w.w & 0xFFFF, s7 = w.w >> 16;
        float4 v0 = gs4[(size_t)s0 * 4 + fl];
        float4 v1 = gs4[(size_t)s1 * 4 + fl];
        float4 v2 = gs4[(size_t)s2 * 4 + fl];
        float4 v3 = gs4[(size_t)s3 * 4 + fl];
        float4 v4 = gs4[(size_t)s4 * 4 + fl];
        float4 v5 = gs4[(size_t)s5 * 4 + fl];
        float4 v6 = gs4[(size_t)s6 * 4 + fl];
        float4 v7 = gs4[(size_t)s7 * 4 + fl];
        acc.x += v0.x + v1.x + v2.x + v3.x + v4.x + v5.x + v6.x + v7.x;
        acc.y += v0.y + v1.y + v2.y + v3.y + v4.y + v5.y + v6.y + v7.y;
        acc.z += v0.z + v1.z + v2.z + v3.z + v4.z + v5.z + v6.z + v7.z;
        acc.w += v0.w + v1.w + v2.w + v3.w + v4.w + v5.w + v6.w + v7.w;
    }
    float4 sf = gs4[(size_t)idxC * 4 + fl];
    acc.x += sf.x; acc.y += sf.y; acc.z += sf.z; acc.w += sf.w;
    float dv = valid ? dinv_s[idx] : 1.0f;
    float sc = last ? dv : dv * dv;
    acc.x *= sc; acc.y *= sc; acc.z *= sc; acc.w *= sc;
    if (valid) go4[(size_t)idx * 4 + fl] = acc;
}

// ---------------------------------------------------------------- out = relu(h) @ Wc + bc (sorted h -> scatter out)
__global__ __launch_bounds__(256) void cls_kernel(const float* __restrict__ h,
                                                  const float* __restrict__ Wc,
                                                  const float* __restrict__ bc,
                                                  const int* __restrict__ nperm,
                                                  float* __restrict__ out, int n, int np1) {
    __shared__ float wc[NHID * NCLS];
    __shared__ float bcs[NCLS];
    int tid = threadIdx.x;
    for (int i = tid; i < NHID * NCLS; i += 256) wc[i] = Wc[i];
    if (tid < NCLS) bcs[tid] = bc[tid];
    __syncthreads();
    int i = blockIdx.x * 256 + tid;
    if (i >= n) return;
    float acc[NCLS];
#pragma unroll
    for (int c = 0; c < NCLS; ++c) acc[c] = bcs[c];
#pragma unroll
    for (int s = 0; s < NSLICE; ++s) {
        const float4* hr = (const float4*)(h + ((size_t)s * np1 + i) * SFEAT);
#pragma unroll
        for (int q = 0; q < 4; ++q) {
            float4 v = hr[q];
            float vs[4] = {fmaxf(v.x, 0.f), fmaxf(v.y, 0.f), fmaxf(v.z, 0.f), fmaxf(v.w, 0.f)};
#pragma unroll
            for (int j = 0; j < 4; ++j)
#pragma unroll
                for (int c = 0; c < NCLS; ++c)
                    acc[c] = fmaf(vs[j], wc[(s * SFEAT + q * 4 + j) * NCLS + c], acc[c]);
        }
    }
    int nd = nperm[i];
#pragma unroll
    for (int c = 0; c < NCLS; ++c) out[(size_t)nd * NCLS + c] = acc[c];
}

// ----------------------------------------------------------------
static inline size_t align256(size_t x) { return (x + 255) & ~(size_t)255; }

extern "C" void kernel_launch(void* const* d_in, const int* in_sizes, int n_in,
                              void* d_out, int out_size, void* d_ws, size_t ws_size,
                              hipStream_t stream) {
    const float* x   = (const float*)d_in[0];
    const int*   ei  = (const int*)d_in[1];     // int64 in reference -> staged as int32
    const float* W1  = (const float*)d_in[2];
    const float* b1  = (const float*)d_in[3];
    const float* Wc  = (const float*)d_in[4];
    const float* bc  = (const float*)d_in[5];
    float*       out = (float*)d_out;

    const int N    = in_sizes[0] / NFEAT;   // 50000
    const int E    = in_sizes[1] / 2;       // 1600000
    const int NP1  = N + 1;                 // +1 dummy row per slice
    const int EPAD = E + 8 * N + 64;        // worst-case padded CSR size

    char* ws = (char*)d_ws;
    size_t off = 0;
    float*          hA     = (float*)(ws + off); off = align256(off + (size_t)NSLICE * NP1 * SFEAT * 4);
    float*          hB     = (float*)(ws + off); off = align256(off + (size_t)NSLICE * NP1 * SFEAT * 4);
    int*            cnt    = (int*)  (ws + off); off = align256(off + (size_t)(N + 256) * 4);
    float*          dinv   = (float*)(ws + off); off = align256(off + (size_t)N * 4);
    int*            pos_s  = (int*)  (ws + off); off = align256(off + (size_t)N * 4);
    int*            nperm  = (int*)  (ws + off); off = align256(off + (size_t)N * 4);
    int*            rank   = (int*)  (ws + off); off = align256(off + (size_t)N * 4);
    int2*           seg_s  = (int2*) (ws + off); off = align256(off + (size_t)N * 8);
    float*          dinv_s = (float*)(ws + off); off = align256(off + (size_t)N * 4);
    unsigned short* esrc   = (unsigned short*)(ws + off); off = align256(off + (size_t)EPAD * 2);

    int* alloc = cnt + N;        // counters region (memset with cnt)
    int* bcnt  = cnt + N + 64;
    int* bpos  = cnt + N + 128;

    hipMemsetAsync(cnt, 0, (size_t)(N + 256) * 4, stream);

    int nbE = (E + 255) / 256;
    deg_kernel<<<8 * nbE, 256, 0, stream>>>(ei, cnt, E, N);
    dinv_kernel<<<(N + 255) / 256, 256, 0, stream>>>(cnt, dinv, N);
    hist_kernel<<<(N + 255) / 256, 256, 0, stream>>>(cnt, bcnt, N);
    scan32_kernel<<<1, 64, 0, stream>>>(bcnt, bpos);
    place_kernel<<<(N + 255) / 256, 256, 0, stream>>>(cnt, bpos, nperm, rank, N);
    alloc_sorted_kernel<<<(N + 255) / 256, 256, 0, stream>>>(nperm, cnt, dinv, alloc,
                                                             seg_s, dinv_s, pos_s, N);
    {
        unsigned int v = ((unsigned)N << 16) | (unsigned)N;
        int nwords = EPAD / 2;
        fill_esrc_kernel<<<(nwords + 255) / 256, 256, 0, stream>>>((unsigned int*)esrc, v, nwords);
    }
    scatter_kernel<<<8 * nbE, 256, 0, stream>>>(ei, rank, pos_s, esrc, E, N);
    init_dummy_kernel<<<1, 256, 0, stream>>>(hA, hB, N, NP1);

    gemm1_kernel<<<(N + 63) / 64, 256, 0, stream>>>(x, W1, b1, dinv, rank, hA, N, NP1);

    int ngrp = (N + 15) / 16;                     // 16 nodes per wave
    int hop_blocks = NSLICE * ((ngrp + 3) / 4);   // 4 waves per block
    for (int i = 0; i < CONV_TIME; ++i) {
        const float* gi = (i & 1) ? hB : hA;
        float*       go = (i & 1) ? hA : hB;
        hop_kernel<<<hop_blocks, 256, 0, stream>>>(gi, go, seg_s, esrc, dinv_s, N, NP1,
                                                   (i == CONV_TIME - 1) ? 1 : 0);
    }

    cls_kernel<<<(N + 255) / 256, 256, 0, stream>>>(hA, Wc, bc, nperm, out, N, NP1);
}